// Round 2
// baseline (933.002 us; speedup 1.0000x reference)
//
#include <hip/hip_runtime.h>

typedef __attribute__((ext_vector_type(8))) __bf16 bf16x8;
typedef __attribute__((ext_vector_type(4))) float f32x4;

#define SLEN 1024
#define DMODEL 1024
#define NHEADS 16
#define DKH 64
#define BATCH 8

__device__ __forceinline__ unsigned short f2bf(float f) {
  unsigned u = __builtin_bit_cast(unsigned, f);
  u += 0x7FFFu + ((u >> 16) & 1u);
  return (unsigned short)(u >> 16);
}

__device__ __forceinline__ void gload_lds16(const void* g, void* l) {
  __builtin_amdgcn_global_load_lds((const __attribute__((address_space(1))) unsigned int*)g,
                                   (__attribute__((address_space(3))) unsigned int*)l, 16, 0, 0);
}

// ---------------- mask dtype detection: flag=1 -> byte mask, 0 -> int32 mask
__global__ void detect_mask(const unsigned char* __restrict__ m, int* __restrict__ flag) {
  int t = threadIdx.x;
  unsigned any = 0;
  for (int j = t; j < 4096; j += 64) any |= m[j * 4 + 1];
  unsigned long long b = __ballot(any != 0);
  if (t == 0) *flag = (b != 0) ? 1 : 0;
}

// ---------------- fp32 -> bf16 bulk convert (8 elems/thread)
__global__ __launch_bounds__(256) void cvt_bf16(const float* __restrict__ in,
                                                unsigned short* __restrict__ o, int n8) {
  int i = blockIdx.x * 256 + threadIdx.x;
  if (i >= n8) return;
  const float4* p = (const float4*)in;
  float4 f0 = p[2 * i], f1 = p[2 * i + 1];
  union { unsigned short us[8]; uint4 v; } pk;
  pk.us[0] = f2bf(f0.x); pk.us[1] = f2bf(f0.y); pk.us[2] = f2bf(f0.z); pk.us[3] = f2bf(f0.w);
  pk.us[4] = f2bf(f1.x); pk.us[5] = f2bf(f1.y); pk.us[6] = f2bf(f1.z); pk.us[7] = f2bf(f1.w);
  ((uint4*)o)[i] = pk.v;
}

// ---------------- transpose V per (b,h): [1024][64] -> [64][1024]
__global__ __launch_bounds__(256) void transpose_v(const unsigned short* __restrict__ Vh,
                                                   unsigned short* __restrict__ Vt) {
  __shared__ unsigned short t[64][65];
  int s0 = blockIdx.x * 64;
  long zo = (long)blockIdx.y * (SLEN * DKH);
  int tid = threadIdx.x;
  for (int i = tid; i < 4096; i += 256) {
    int r = i >> 6, c = i & 63;
    t[r][c] = Vh[zo + (long)(s0 + r) * 64 + c];
  }
  __syncthreads();
  for (int i = tid; i < 4096; i += 256) {
    int d = i >> 6, sc = i & 63;
    Vt[zo + (long)d * SLEN + s0 + sc] = t[sc][d];
  }
}

// ---------------- NT bf16 MFMA GEMM for projections / FC
// EPI: 0 = proj -> bf16 head layout (*scale), 1 = FC -> fp32 row-major
template<int EPI>
__global__ __launch_bounds__(256) void gemm_nt(
    const unsigned short* __restrict__ Ab, const unsigned short* __restrict__ Bb,
    int K, float* __restrict__ of32, unsigned short* __restrict__ obf, float scale) {
  constexpr int BM = 128, BN = 128, BKE = 32;
  constexpr int WM = 64, WN = 64, FM = 4, FN = 4;

  const int m0 = blockIdx.x * BM;
  const int n0 = blockIdx.y * BN;
  const int tid = threadIdx.x;
  const int l = tid & 63;
  const int w = tid >> 6;
  const int wr = w >> 1, wc = w & 1;

  __shared__ __attribute__((aligned(16))) unsigned short As[BM * BKE];
  __shared__ __attribute__((aligned(16))) unsigned short Bs[BN * BKE];

  f32x4 acc[FM][FN];
#pragma unroll
  for (int i = 0; i < FM; i++)
#pragma unroll
    for (int j = 0; j < FN; j++)
      acc[i][j] = f32x4{0.f, 0.f, 0.f, 0.f};

  const int kread = (l >> 4) << 3;
  const int rl = l & 15;

  for (int k0 = 0; k0 < K; k0 += BKE) {
    __syncthreads();
#pragma unroll
    for (int i = 0; i < 2; i++) {
      int c = tid + i * 256;
      int row = c >> 2, kc = (c & 3) << 3;
      gload_lds16(Ab + (long)(m0 + row) * K + (k0 + kc), &As[c * 8]);
    }
#pragma unroll
    for (int i = 0; i < 2; i++) {
      int c = tid + i * 256;
      int row = c >> 2, kc = (c & 3) << 3;
      gload_lds16(Bb + (long)(n0 + row) * K + (k0 + kc), &Bs[c * 8]);
    }
    __syncthreads();

    bf16x8 af[FM], bfr[FN];
#pragma unroll
    for (int mi = 0; mi < FM; mi++)
      af[mi] = *(const bf16x8*)&As[(wr * WM + mi * 16 + rl) * BKE + kread];
#pragma unroll
    for (int ni = 0; ni < FN; ni++)
      bfr[ni] = *(const bf16x8*)&Bs[(wc * WN + ni * 16 + rl) * BKE + kread];
#pragma unroll
    for (int mi = 0; mi < FM; mi++)
#pragma unroll
      for (int ni = 0; ni < FN; ni++)
        acc[mi][ni] = __builtin_amdgcn_mfma_f32_16x16x32_bf16(af[mi], bfr[ni], acc[mi][ni], 0, 0, 0);
  }

  const int r0 = (l >> 4) << 2;
  const int cc = l & 15;
#pragma unroll
  for (int mi = 0; mi < FM; mi++) {
#pragma unroll
    for (int ni = 0; ni < FN; ni++) {
      f32x4 v = acc[mi][ni];
      int row = m0 + wr * WM + mi * 16 + r0;
      int col = n0 + wc * WN + ni * 16 + cc;
#pragma unroll
      for (int j = 0; j < 4; j++) {
        float val = v[j];
        int rr = row + j;
        if constexpr (EPI == 0) {
          long idx = (((long)((rr >> 10) * 16 + (col >> 6)) * 1024 + (rr & 1023)) << 6) + (col & 63);
          obf[idx] = f2bf(val * scale);
        } else {
          of32[((long)rr << 10) + col] = val;
        }
      }
    }
  }
}

// ---------------- fused scores+mask+softmax+attnwrite+PV
// block: 256 thr (4 waves), one (b,h), 16 query rows, full 1024 cols
__global__ __launch_bounds__(256) void attn_fused(
    const unsigned short* __restrict__ Qh, const unsigned short* __restrict__ Kh,
    const unsigned short* __restrict__ Vt, const unsigned char* __restrict__ mask,
    const int* __restrict__ flagp, float* __restrict__ attn,
    unsigned short* __restrict__ ctx) {
  const int z = blockIdx.y;  // b*16+h
  const int q0 = blockIdx.x * 16;
  const int b = z >> 4, h = z & 15;
  const int tid = threadIdx.x, l = tid & 63, w = tid >> 6;
  const int rl = l & 15, hi = l >> 4;

  __shared__ __attribute__((aligned(16))) unsigned short Ks[128 * 64];  // 16 KB (aliased as Vs)
  __shared__ __attribute__((aligned(16))) unsigned short Pl[16 * 1024]; // 32 KB swizzled P
  __shared__ float red[2][4][16];

  const long bh_off = (long)z * (SLEN * DKH);

  // Q A-fragments (rows q0..q0+15, two 32-wide k-steps)
  bf16x8 qf[2];
  {
    const unsigned short* qp = Qh + bh_off + (long)(q0 + rl) * 64 + hi * 8;
    qf[0] = *(const bf16x8*)qp;
    qf[1] = *(const bf16x8*)(qp + 32);
  }

  f32x4 acc[16];
#pragma unroll
  for (int i = 0; i < 16; i++) acc[i] = f32x4{0.f, 0.f, 0.f, 0.f};

  // ---- phase 1: scores = Q @ K^T over 8 K-row stages of 128
#pragma unroll
  for (int s = 0; s < 8; s++) {
    __syncthreads();
#pragma unroll
    for (int i = 0; i < 4; i++) {
      int o = (i * 256 + tid) * 16;  // linear LDS byte offset
      int row = o >> 7;              // 0..127
      int cb = o & 127;
      int cbs = cb ^ ((row & 7) << 4);  // pre-swizzled global source
      gload_lds16(Kh + bh_off + (long)(s * 128 + row) * 64 + (cbs >> 1), (char*)Ks + o);
    }
    __syncthreads();
#pragma unroll
    for (int f = 0; f < 2; f++) {
      int brow = (f * 4 + w) * 16 + rl;  // K row within stage tile
#pragma unroll
      for (int ks = 0; ks < 2; ks++) {
        int cbyte = (ks * 64 + hi * 16) ^ ((brow & 7) << 4);
        bf16x8 bf = *(const bf16x8*)((const char*)Ks + brow * 128 + cbyte);
        acc[s * 2 + f] = __builtin_amdgcn_mfma_f32_16x16x32_bf16(qf[ks], bf, acc[s * 2 + f], 0, 0, 0);
      }
    }
  }

  // ---- mask + row max
  const int flag = *flagp;
  const long mbase = ((long)b << 20) + ((long)q0 << 10);
  float mx[4] = {-3e38f, -3e38f, -3e38f, -3e38f};
#pragma unroll
  for (int ni = 0; ni < 16; ni++) {
    int col = (ni * 4 + w) * 16 + rl;
#pragma unroll
    for (int j = 0; j < 4; j++) {
      int r = hi * 4 + j;
      long midx = mbase + ((long)r << 10) + col;
      bool m_ = flag ? (mask[midx] != 0) : (((const int*)mask)[midx] != 0);
      if (m_) acc[ni][j] = -1.0e9f;
      mx[j] = fmaxf(mx[j], acc[ni][j]);
    }
  }
#pragma unroll
  for (int j = 0; j < 4; j++)
#pragma unroll
    for (int o = 1; o <= 8; o <<= 1) mx[j] = fmaxf(mx[j], __shfl_xor(mx[j], o));
  if (rl == 0) {
#pragma unroll
    for (int j = 0; j < 4; j++) red[0][w][hi * 4 + j] = mx[j];
  }
  __syncthreads();
  float m4[4];
#pragma unroll
  for (int j = 0; j < 4; j++) {
    int r = hi * 4 + j;
    m4[j] = fmaxf(fmaxf(red[0][0][r], red[0][1][r]), fmaxf(red[0][2][r], red[0][3][r]));
  }

  // ---- exp + row sum
  float sum[4] = {0.f, 0.f, 0.f, 0.f};
#pragma unroll
  for (int ni = 0; ni < 16; ni++)
#pragma unroll
    for (int j = 0; j < 4; j++) {
      float e = __expf(acc[ni][j] - m4[j]);
      acc[ni][j] = e;
      sum[j] += e;
    }
#pragma unroll
  for (int j = 0; j < 4; j++)
#pragma unroll
    for (int o = 1; o <= 8; o <<= 1) sum[j] += __shfl_xor(sum[j], o);
  if (rl == 0) {
#pragma unroll
    for (int j = 0; j < 4; j++) red[1][w][hi * 4 + j] = sum[j];
  }
  __syncthreads();
  float inv[4];
#pragma unroll
  for (int j = 0; j < 4; j++) {
    int r = hi * 4 + j;
    inv[j] = 1.0f / (red[1][0][r] + red[1][1][r] + red[1][2][r] + red[1][3][r]);
  }

  // ---- normalize: write attn (global) + P bf16 (LDS, swizzled)
  const long abase = ((long)z << 20) + ((long)q0 << 10);
#pragma unroll
  for (int ni = 0; ni < 16; ni++) {
    int col = (ni * 4 + w) * 16 + rl;
#pragma unroll
    for (int j = 0; j < 4; j++) {
      int r = hi * 4 + j;
      float p = acc[ni][j] * inv[j];
      attn[abase + ((long)r << 10) + col] = p;
      int pb = (col * 2) ^ ((r & 7) << 4);
      *(unsigned short*)((char*)Pl + r * 2048 + pb) = f2bf(p);
    }
  }

  // ---- phase 2: ctx = P @ V  (Vs tiles aliased into Ks)
  f32x4 c2 = f32x4{0.f, 0.f, 0.f, 0.f};
  for (int k0 = 0; k0 < 1024; k0 += 64) {
    __syncthreads();
#pragma unroll
    for (int i = 0; i < 2; i++) {
      int o = (i * 256 + tid) * 16;
      int row = o >> 7;  // d 0..63
      int cb = o & 127;
      int cbs = cb ^ ((row & 7) << 4);
      gload_lds16(Vt + bh_off + (long)row * 1024 + k0 + (cbs >> 1), (char*)Ks + o);
    }
    __syncthreads();
#pragma unroll
    for (int ks = 0; ks < 2; ks++) {
      int kb = ((k0 + ks * 32 + hi * 8) * 2) ^ ((rl & 7) << 4);
      bf16x8 af = *(const bf16x8*)((const char*)Pl + rl * 2048 + kb);
      int vrow = w * 16 + rl;
      int vb = (ks * 64 + hi * 16) ^ ((vrow & 7) << 4);
      bf16x8 bf = *(const bf16x8*)((const char*)Ks + vrow * 128 + vb);
      c2 = __builtin_amdgcn_mfma_f32_16x16x32_bf16(af, bf, c2, 0, 0, 0);
    }
  }
#pragma unroll
  for (int j = 0; j < 4; j++) {
    int r = q0 + hi * 4 + j;
    long idx = ((long)(b * 1024 + r) << 10) + h * 64 + w * 16 + rl;
    ctx[idx] = f2bf(c2[j]);
  }
}

// ---------------- residual + LayerNorm, one block per row
__global__ __launch_bounds__(256) void ln_kernel(const float* __restrict__ fc,
                                                 const float* __restrict__ inQ,
                                                 const float* __restrict__ gamma,
                                                 const float* __restrict__ beta,
                                                 float* __restrict__ out) {
  long base = (long)blockIdx.x << 10;
  int tid = threadIdx.x, l = tid & 63, w = tid >> 6;
  float4 a = ((const float4*)(fc + base))[tid];
  float4 b = ((const float4*)(inQ + base))[tid];
  float4 x; x.x = a.x + b.x; x.y = a.y + b.y; x.z = a.z + b.z; x.w = a.w + b.w;
  float s = x.x + x.y + x.z + x.w;
  float q = x.x * x.x + x.y * x.y + x.z * x.z + x.w * x.w;
  for (int o = 32; o; o >>= 1) { s += __shfl_xor(s, o); q += __shfl_xor(q, o); }
  __shared__ float rs[4], rq[4];
  if (l == 0) { rs[w] = s; rq[w] = q; }
  __syncthreads();
  s = rs[0] + rs[1] + rs[2] + rs[3];
  q = rq[0] + rq[1] + rq[2] + rq[3];
  float mu = s * (1.0f / 1024.0f);
  float var = q * (1.0f / 1024.0f) - mu * mu;
  float rstd = rsqrtf(var + 1e-5f);
  float4 g = ((const float4*)gamma)[tid];
  float4 be = ((const float4*)beta)[tid];
  float4 o4;
  o4.x = (x.x - mu) * rstd * g.x + be.x;
  o4.y = (x.y - mu) * rstd * g.y + be.y;
  o4.z = (x.z - mu) * rstd * g.z + be.z;
  o4.w = (x.w - mu) * rstd * g.w + be.w;
  ((float4*)(out + base))[tid] = o4;
}

extern "C" void kernel_launch(void* const* d_in, const int* in_sizes, int n_in,
                              void* d_out, int out_size, void* d_ws, size_t ws_size,
                              hipStream_t stream) {
  const float* inQ = (const float*)d_in[0];
  const float* inK = (const float*)d_in[1];
  const float* inV = (const float*)d_in[2];
  const unsigned char* mask = (const unsigned char*)d_in[3];
  const float* WQ = (const float*)d_in[4];
  const float* WK = (const float*)d_in[5];
  const float* WV = (const float*)d_in[6];
  const float* WFC = (const float*)d_in[7];
  const float* gamma = (const float*)d_in[8];
  const float* beta = (const float*)d_in[9];

  float* out = (float*)d_out;
  float* attn = out + (size_t)BATCH * SLEN * DMODEL;

  char* ws = (char*)d_ws;
  size_t off = 256;
  int* flag = (int*)ws;
  auto take = [&](size_t bytes) { char* p = ws + off; off += (bytes + 255) & ~255UL; return p; };
  const size_t XB = (size_t)BATCH * SLEN * DMODEL * 2;
  const size_t WB = (size_t)DMODEL * DMODEL * 2;
  unsigned short* Xq = (unsigned short*)take(XB);
  unsigned short* Xk = (unsigned short*)take(XB);
  unsigned short* Xv = (unsigned short*)take(XB);
  unsigned short* Wqb = (unsigned short*)take(WB);
  unsigned short* Wkb = (unsigned short*)take(WB);
  unsigned short* Wvb = (unsigned short*)take(WB);
  unsigned short* Wfcb = (unsigned short*)take(WB);
  unsigned short* Qh = (unsigned short*)take(XB);
  unsigned short* Kh = (unsigned short*)take(XB);
  unsigned short* Vh = (unsigned short*)take(XB);
  unsigned short* Vt = (unsigned short*)take(XB);
  unsigned short* ctx = (unsigned short*)take(XB);
  float* fc = (float*)take((size_t)BATCH * SLEN * DMODEL * 4);

  detect_mask<<<1, 64, 0, stream>>>(mask, flag);

  const int n8x = BATCH * SLEN * DMODEL / 8;
  const int n8w = DMODEL * DMODEL / 8;
  cvt_bf16<<<n8x / 256, 256, 0, stream>>>(inQ, Xq, n8x);
  cvt_bf16<<<n8x / 256, 256, 0, stream>>>(inK, Xk, n8x);
  cvt_bf16<<<n8x / 256, 256, 0, stream>>>(inV, Xv, n8x);
  cvt_bf16<<<n8w / 256, 256, 0, stream>>>(WQ, Wqb, n8w);
  cvt_bf16<<<n8w / 256, 256, 0, stream>>>(WK, Wkb, n8w);
  cvt_bf16<<<n8w / 256, 256, 0, stream>>>(WV, Wvb, n8w);
  cvt_bf16<<<n8w / 256, 256, 0, stream>>>(WFC, Wfcb, n8w);

  dim3 gp(64, 8);
  gemm_nt<0><<<gp, 256, 0, stream>>>(Xq, Wqb, 1024, nullptr, Qh, 0.125f);
  gemm_nt<0><<<gp, 256, 0, stream>>>(Xk, Wkb, 1024, nullptr, Kh, 1.0f);
  gemm_nt<0><<<gp, 256, 0, stream>>>(Xv, Wvb, 1024, nullptr, Vh, 1.0f);

  transpose_v<<<dim3(16, 128), 256, 0, stream>>>(Vh, Vt);

  attn_fused<<<dim3(64, 128), 256, 0, stream>>>(Qh, Kh, Vt, mask, flag, attn, ctx);

  gemm_nt<1><<<gp, 256, 0, stream>>>(ctx, Wfcb, 1024, fc, nullptr, 1.0f);

  ln_kernel<<<BATCH * SLEN, 256, 0, stream>>>(fc, inQ, gamma, beta, out);
}

// Round 3
// 551.393 us; speedup vs baseline: 1.6921x; 1.6921x over previous
//
#include <hip/hip_runtime.h>

typedef __attribute__((ext_vector_type(8))) __bf16 bf16x8;
typedef __attribute__((ext_vector_type(4))) float f32x4;

#define SLEN 1024
#define DMODEL 1024
#define NHEADS 16
#define DKH 64
#define BATCH 8

__device__ __forceinline__ unsigned short f2bf(float f) {
  unsigned u = __builtin_bit_cast(unsigned, f);
  u += 0x7FFFu + ((u >> 16) & 1u);
  return (unsigned short)(u >> 16);
}

__device__ __forceinline__ void gload_lds16(const void* g, void* l) {
  __builtin_amdgcn_global_load_lds((const __attribute__((address_space(1))) unsigned int*)g,
                                   (__attribute__((address_space(3))) unsigned int*)l, 16, 0, 0);
}

// ---------------- mask dtype detection: flag=1 -> byte mask, 0 -> int32 mask
__global__ void detect_mask(const unsigned char* __restrict__ m, int* __restrict__ flag) {
  int t = threadIdx.x;
  unsigned any = 0;
  for (int j = t; j < 4096; j += 64) any |= m[j * 4 + 1];
  unsigned long long b = __ballot(any != 0);
  if (t == 0) *flag = (b != 0) ? 1 : 0;
}

// ---------------- bit-pack mask: one block per (b,q) row of 1024 -> 32 words
__global__ __launch_bounds__(256) void mask_pack(const unsigned char* __restrict__ m,
                                                 const int* __restrict__ flagp,
                                                 unsigned* __restrict__ mb) {
  long base = (long)blockIdx.x << 10;
  int tid = threadIdx.x;
  int flag = *flagp;
  unsigned nib;
  if (flag) {
    uchar4 v = ((const uchar4*)(m + base))[tid];
    nib = (v.x ? 1u : 0u) | (v.y ? 2u : 0u) | (v.z ? 4u : 0u) | (v.w ? 8u : 0u);
  } else {
    int4 v = ((const int4*)((const int*)m + base))[tid];
    nib = (v.x ? 1u : 0u) | (v.y ? 2u : 0u) | (v.z ? 4u : 0u) | (v.w ? 8u : 0u);
  }
  __shared__ unsigned char nibs[256];
  nibs[tid] = (unsigned char)nib;
  __syncthreads();
  if (tid < 32) {
    unsigned wv = 0;
#pragma unroll
    for (int i = 0; i < 8; i++) wv |= ((unsigned)nibs[tid * 8 + i]) << (i * 4);
    mb[((long)blockIdx.x << 5) + tid] = wv;
  }
}

// ---------------- fp32 -> bf16 bulk convert, up to 4 tensors via blockIdx.y
__global__ __launch_bounds__(256) void cvt_bf16_multi(
    const float* __restrict__ p0, const float* __restrict__ p1,
    const float* __restrict__ p2, const float* __restrict__ p3,
    unsigned short* __restrict__ o0, unsigned short* __restrict__ o1,
    unsigned short* __restrict__ o2, unsigned short* __restrict__ o3, int n8) {
  int which = blockIdx.y;
  const float* in = which == 0 ? p0 : which == 1 ? p1 : which == 2 ? p2 : p3;
  unsigned short* o = which == 0 ? o0 : which == 1 ? o1 : which == 2 ? o2 : o3;
  int i = blockIdx.x * 256 + threadIdx.x;
  if (i >= n8) return;
  const float4* p = (const float4*)in;
  float4 f0 = p[2 * i], f1 = p[2 * i + 1];
  union { unsigned short us[8]; uint4 v; } pk;
  pk.us[0] = f2bf(f0.x); pk.us[1] = f2bf(f0.y); pk.us[2] = f2bf(f0.z); pk.us[3] = f2bf(f0.w);
  pk.us[4] = f2bf(f1.x); pk.us[5] = f2bf(f1.y); pk.us[6] = f2bf(f1.z); pk.us[7] = f2bf(f1.w);
  ((uint4*)o)[i] = pk.v;
}

// ---------------- transpose V per (b,h): [1024][64] -> [64][1024]
__global__ __launch_bounds__(256) void transpose_v(const unsigned short* __restrict__ Vh,
                                                   unsigned short* __restrict__ Vt) {
  __shared__ unsigned short t[64][65];
  int s0 = blockIdx.x * 64;
  long zo = (long)blockIdx.y * (SLEN * DKH);
  int tid = threadIdx.x;
  for (int i = tid; i < 4096; i += 256) {
    int r = i >> 6, c = i & 63;
    t[r][c] = Vh[zo + (long)(s0 + r) * 64 + c];
  }
  __syncthreads();
  for (int i = tid; i < 4096; i += 256) {
    int d = i >> 6, sc = i & 63;
    Vt[zo + (long)d * SLEN + s0 + sc] = t[sc][d];
  }
}

// ---------------- NT bf16 MFMA GEMM for projections / FC
// EPI: 0 = proj -> bf16 head layout (*scale), 1 = FC -> fp32 row-major
template<int EPI>
__global__ __launch_bounds__(256) void gemm_nt(
    const unsigned short* __restrict__ Ab, const unsigned short* __restrict__ Bb,
    int K, float* __restrict__ of32, unsigned short* __restrict__ obf, float scale) {
  constexpr int BM = 128, BN = 128, BKE = 32;
  constexpr int WM = 64, WN = 64, FM = 4, FN = 4;

  const int m0 = blockIdx.x * BM;
  const int n0 = blockIdx.y * BN;
  const int tid = threadIdx.x;
  const int l = tid & 63;
  const int w = tid >> 6;
  const int wr = w >> 1, wc = w & 1;

  __shared__ __attribute__((aligned(16))) unsigned short As[BM * BKE];
  __shared__ __attribute__((aligned(16))) unsigned short Bs[BN * BKE];

  f32x4 acc[FM][FN];
#pragma unroll
  for (int i = 0; i < FM; i++)
#pragma unroll
    for (int j = 0; j < FN; j++)
      acc[i][j] = f32x4{0.f, 0.f, 0.f, 0.f};

  const int kread = (l >> 4) << 3;
  const int rl = l & 15;

  for (int k0 = 0; k0 < K; k0 += BKE) {
    __syncthreads();
#pragma unroll
    for (int i = 0; i < 2; i++) {
      int c = tid + i * 256;
      int row = c >> 2, kc = (c & 3) << 3;
      gload_lds16(Ab + (long)(m0 + row) * K + (k0 + kc), &As[c * 8]);
    }
#pragma unroll
    for (int i = 0; i < 2; i++) {
      int c = tid + i * 256;
      int row = c >> 2, kc = (c & 3) << 3;
      gload_lds16(Bb + (long)(n0 + row) * K + (k0 + kc), &Bs[c * 8]);
    }
    __syncthreads();

    bf16x8 af[FM], bfr[FN];
#pragma unroll
    for (int mi = 0; mi < FM; mi++)
      af[mi] = *(const bf16x8*)&As[(wr * WM + mi * 16 + rl) * BKE + kread];
#pragma unroll
    for (int ni = 0; ni < FN; ni++)
      bfr[ni] = *(const bf16x8*)&Bs[(wc * WN + ni * 16 + rl) * BKE + kread];
#pragma unroll
    for (int mi = 0; mi < FM; mi++)
#pragma unroll
      for (int ni = 0; ni < FN; ni++)
        acc[mi][ni] = __builtin_amdgcn_mfma_f32_16x16x32_bf16(af[mi], bfr[ni], acc[mi][ni], 0, 0, 0);
  }

  const int r0 = (l >> 4) << 2;
  const int cc = l & 15;
#pragma unroll
  for (int mi = 0; mi < FM; mi++) {
#pragma unroll
    for (int ni = 0; ni < FN; ni++) {
      f32x4 v = acc[mi][ni];
      int row = m0 + wr * WM + mi * 16 + r0;
      int col = n0 + wc * WN + ni * 16 + cc;
#pragma unroll
      for (int j = 0; j < 4; j++) {
        float val = v[j];
        int rr = row + j;
        if constexpr (EPI == 0) {
          long idx = (((long)((rr >> 10) * 16 + (col >> 6)) * 1024 + (rr & 1023)) << 6) + (col & 63);
          obf[idx] = f2bf(val * scale);
        } else {
          of32[((long)rr << 10) + col] = val;
        }
      }
    }
  }
}

// ---------------- scores + mask + softmax -> attn (fp32)
// block: 512 thr (2 quads of 4 waves), one (b,h), 512 q-rows; K fully in LDS
__global__ __launch_bounds__(512) void attn_scores(
    const unsigned short* __restrict__ Qh, const unsigned short* __restrict__ Kh,
    const unsigned* __restrict__ mb, float* __restrict__ attn) {
  const int z = blockIdx.y;
  const int b = z >> 4;
  const int tid = threadIdx.x;
  const int quad = tid >> 8;
  const int c = (tid >> 6) & 3;
  const int l = tid & 63, rl = l & 15, hi = l >> 4;

  __shared__ __attribute__((aligned(16))) unsigned short Ks[SLEN * DKH];  // 128 KB
  __shared__ float redm[2][2][4][16];
  __shared__ float reds[2][2][4][16];

  const long bh_off = (long)z * (SLEN * DKH);

  // stage ALL of K (1024x64 bf16, XOR-swizzled via pre-swizzled source)
#pragma unroll
  for (int i = 0; i < 16; i++) {
    int o = (i * 512 + tid) * 16;
    int row = o >> 7, cb = o & 127;
    int cbs = cb ^ ((row & 7) << 4);
    gload_lds16(Kh + bh_off + (long)row * 64 + (cbs >> 1), (char*)Ks + o);
  }
  __syncthreads();

  const int qbase = blockIdx.x * 512 + quad * 256;
  const long abase = (long)z << 20;

  for (int s = 0; s < 16; s++) {
    const int q0 = qbase + s * 16;
    const unsigned short* qp = Qh + bh_off + (long)(q0 + rl) * 64 + hi * 8;
    bf16x8 qf0 = *(const bf16x8*)qp;
    bf16x8 qf1 = *(const bf16x8*)(qp + 32);

    f32x4 acc[16];
#pragma unroll
    for (int t = 0; t < 16; t++) acc[t] = f32x4{0.f, 0.f, 0.f, 0.f};

#pragma unroll
    for (int t = 0; t < 16; t++) {
      int row = c * 256 + t * 16 + rl;
      int sw = (row & 7) << 4;
      bf16x8 b0 = *(const bf16x8*)((const char*)Ks + row * 128 + ((hi * 16) ^ sw));
      bf16x8 b1 = *(const bf16x8*)((const char*)Ks + row * 128 + ((64 + hi * 16) ^ sw));
      acc[t] = __builtin_amdgcn_mfma_f32_16x16x32_bf16(qf0, b0, acc[t], 0, 0, 0);
      acc[t] = __builtin_amdgcn_mfma_f32_16x16x32_bf16(qf1, b1, acc[t], 0, 0, 0);
    }

    // mask words: 8 per row-quarter, bit k&31 of word k>>5
    unsigned mw[4][8];
#pragma unroll
    for (int j = 0; j < 4; j++) {
      int q = q0 + hi * 4 + j;
      const uint4* wp = (const uint4*)(mb + (((long)((b << 10) | q)) << 5) + c * 8);
      uint4 w0 = wp[0], w1 = wp[1];
      mw[j][0] = w0.x; mw[j][1] = w0.y; mw[j][2] = w0.z; mw[j][3] = w0.w;
      mw[j][4] = w1.x; mw[j][5] = w1.y; mw[j][6] = w1.z; mw[j][7] = w1.w;
    }

    float mx[4] = {-3.0e38f, -3.0e38f, -3.0e38f, -3.0e38f};
#pragma unroll
    for (int t = 0; t < 16; t++) {
#pragma unroll
      for (int j = 0; j < 4; j++) {
        float v = ((mw[j][t >> 1] >> (rl + ((t & 1) << 4))) & 1u) ? -1.0e9f : acc[t][j];
        acc[t][j] = v;
        mx[j] = fmaxf(mx[j], v);
      }
    }
#pragma unroll
    for (int j = 0; j < 4; j++) {
      mx[j] = fmaxf(mx[j], __shfl_xor(mx[j], 1));
      mx[j] = fmaxf(mx[j], __shfl_xor(mx[j], 2));
      mx[j] = fmaxf(mx[j], __shfl_xor(mx[j], 4));
      mx[j] = fmaxf(mx[j], __shfl_xor(mx[j], 8));
    }
    if (rl == 0) {
#pragma unroll
      for (int j = 0; j < 4; j++) redm[s & 1][quad][c][hi * 4 + j] = mx[j];
    }
    __syncthreads();
    float m4[4];
#pragma unroll
    for (int j = 0; j < 4; j++) {
      int r = hi * 4 + j;
      m4[j] = fmaxf(fmaxf(redm[s & 1][quad][0][r], redm[s & 1][quad][1][r]),
                    fmaxf(redm[s & 1][quad][2][r], redm[s & 1][quad][3][r]));
    }

    float sum[4] = {0.f, 0.f, 0.f, 0.f};
#pragma unroll
    for (int t = 0; t < 16; t++)
#pragma unroll
      for (int j = 0; j < 4; j++) {
        float e = __expf(acc[t][j] - m4[j]);
        acc[t][j] = e;
        sum[j] += e;
      }
#pragma unroll
    for (int j = 0; j < 4; j++) {
      sum[j] += __shfl_xor(sum[j], 1);
      sum[j] += __shfl_xor(sum[j], 2);
      sum[j] += __shfl_xor(sum[j], 4);
      sum[j] += __shfl_xor(sum[j], 8);
    }
    if (rl == 0) {
#pragma unroll
      for (int j = 0; j < 4; j++) reds[s & 1][quad][c][hi * 4 + j] = sum[j];
    }
    __syncthreads();
    float inv[4];
#pragma unroll
    for (int j = 0; j < 4; j++) {
      int r = hi * 4 + j;
      inv[j] = 1.0f / (reds[s & 1][quad][0][r] + reds[s & 1][quad][1][r] +
                       reds[s & 1][quad][2][r] + reds[s & 1][quad][3][r]);
    }

#pragma unroll
    for (int t = 0; t < 16; t++) {
      int col = c * 256 + t * 16 + rl;
#pragma unroll
      for (int j = 0; j < 4; j++) {
        attn[abase + (((long)(q0 + hi * 4 + j)) << 10) + col] = acc[t][j] * inv[j];
      }
    }
  }
}

// ---------------- PV GEMM: ctx[q, h*64+d] = sum_k attn[q,k] * Vt[d,k]
// 128x64 tile, BK=64, fp32 A converted in reg-staging, swizzled LDS
__global__ __launch_bounds__(256) void pv_gemm(const float* __restrict__ attn,
                                               const unsigned short* __restrict__ Vt,
                                               unsigned short* __restrict__ ctx) {
  const int z = blockIdx.y;
  const int m0 = blockIdx.x * 128;
  const int b = z >> 4, h = z & 15;
  const int tid = threadIdx.x, l = tid & 63, w = tid >> 6;
  const int rl = l & 15, hi = l >> 4;

  __shared__ __attribute__((aligned(16))) unsigned short As[128 * 64];  // 16 KB swz
  __shared__ __attribute__((aligned(16))) unsigned short Bs[64 * 64];   // 8 KB swz

  const float* Ab = attn + ((long)z << 20);
  const unsigned short* Bb = Vt + (long)z * (SLEN * DKH);

  f32x4 acc[2][4];
#pragma unroll
  for (int i = 0; i < 2; i++)
#pragma unroll
    for (int j = 0; j < 4; j++) acc[i][j] = f32x4{0.f, 0.f, 0.f, 0.f};

  for (int k0 = 0; k0 < 1024; k0 += 64) {
    __syncthreads();
    // A: 128 rows x 64 k fp32 -> bf16, swizzled LDS write
#pragma unroll
    for (int i = 0; i < 4; i++) {
      int cch = i * 256 + tid;
      int row = cch >> 3, kc = (cch & 7) << 3;
      const float* src = Ab + ((long)(m0 + row) << 10) + k0 + kc;
      float4 f0 = ((const float4*)src)[0];
      float4 f1 = ((const float4*)src)[1];
      union { unsigned short us[8]; uint4 v; } pk;
      pk.us[0] = f2bf(f0.x); pk.us[1] = f2bf(f0.y); pk.us[2] = f2bf(f0.z); pk.us[3] = f2bf(f0.w);
      pk.us[4] = f2bf(f1.x); pk.us[5] = f2bf(f1.y); pk.us[6] = f2bf(f1.z); pk.us[7] = f2bf(f1.w);
      *(uint4*)&As[row * 64 + (kc ^ ((row & 7) << 3))] = pk.v;
    }
    // B: 64 rows x 64 k via gload_lds, pre-swizzled source
#pragma unroll
    for (int i = 0; i < 2; i++) {
      int cch = i * 256 + tid;
      int o = cch * 16;
      int row = o >> 7, cb = o & 127;
      int cbs = cb ^ ((row & 7) << 4);
      gload_lds16(Bb + (long)row * SLEN + k0 + (cbs >> 1), (char*)Bs + o);
    }
    __syncthreads();

#pragma unroll
    for (int ks = 0; ks < 2; ks++) {
      bf16x8 af[2], bfr[4];
#pragma unroll
      for (int mi = 0; mi < 2; mi++) {
        int ar = w * 32 + mi * 16 + rl;
        af[mi] = *(const bf16x8*)&As[ar * 64 + ((ks * 32 + hi * 8) ^ ((ar & 7) << 3))];
      }
#pragma unroll
      for (int ni = 0; ni < 4; ni++) {
        int br = ni * 16 + rl;
        bfr[ni] = *(const bf16x8*)((const char*)Bs + br * 128 + ((ks * 64 + hi * 16) ^ ((br & 7) << 4)));
      }
#pragma unroll
      for (int mi = 0; mi < 2; mi++)
#pragma unroll
        for (int ni = 0; ni < 4; ni++)
          acc[mi][ni] = __builtin_amdgcn_mfma_f32_16x16x32_bf16(af[mi], bfr[ni], acc[mi][ni], 0, 0, 0);
    }
  }

#pragma unroll
  for (int mi = 0; mi < 2; mi++)
#pragma unroll
    for (int ni = 0; ni < 4; ni++)
#pragma unroll
      for (int j = 0; j < 4; j++) {
        int row = m0 + w * 32 + mi * 16 + hi * 4 + j;
        int col = ni * 16 + rl;
        ctx[(((long)(b * 1024 + row)) << 10) + h * 64 + col] = f2bf(acc[mi][ni][j]);
      }
}

// ---------------- residual + LayerNorm, one block per row
__global__ __launch_bounds__(256) void ln_kernel(const float* __restrict__ fc,
                                                 const float* __restrict__ inQ,
                                                 const float* __restrict__ gamma,
                                                 const float* __restrict__ beta,
                                                 float* __restrict__ out) {
  long base = (long)blockIdx.x << 10;
  int tid = threadIdx.x, l = tid & 63, w = tid >> 6;
  float4 a = ((const float4*)(fc + base))[tid];
  float4 b = ((const float4*)(inQ + base))[tid];
  float4 x; x.x = a.x + b.x; x.y = a.y + b.y; x.z = a.z + b.z; x.w = a.w + b.w;
  float s = x.x + x.y + x.z + x.w;
  float q = x.x * x.x + x.y * x.y + x.z * x.z + x.w * x.w;
  for (int o = 32; o; o >>= 1) { s += __shfl_xor(s, o); q += __shfl_xor(q, o); }
  __shared__ float rs[4], rq[4];
  if (l == 0) { rs[w] = s; rq[w] = q; }
  __syncthreads();
  s = rs[0] + rs[1] + rs[2] + rs[3];
  q = rq[0] + rq[1] + rq[2] + rq[3];
  float mu = s * (1.0f / 1024.0f);
  float var = q * (1.0f / 1024.0f) - mu * mu;
  float rstd = rsqrtf(var + 1e-5f);
  float4 g = ((const float4*)gamma)[tid];
  float4 be = ((const float4*)beta)[tid];
  float4 o4;
  o4.x = (x.x - mu) * rstd * g.x + be.x;
  o4.y = (x.y - mu) * rstd * g.y + be.y;
  o4.z = (x.z - mu) * rstd * g.z + be.z;
  o4.w = (x.w - mu) * rstd * g.w + be.w;
  ((float4*)(out + base))[tid] = o4;
}

extern "C" void kernel_launch(void* const* d_in, const int* in_sizes, int n_in,
                              void* d_out, int out_size, void* d_ws, size_t ws_size,
                              hipStream_t stream) {
  const float* inQ = (const float*)d_in[0];
  const float* inK = (const float*)d_in[1];
  const float* inV = (const float*)d_in[2];
  const unsigned char* mask = (const unsigned char*)d_in[3];
  const float* WQ = (const float*)d_in[4];
  const float* WK = (const float*)d_in[5];
  const float* WV = (const float*)d_in[6];
  const float* WFC = (const float*)d_in[7];
  const float* gamma = (const float*)d_in[8];
  const float* beta = (const float*)d_in[9];

  float* out = (float*)d_out;
  float* attn = out + (size_t)BATCH * SLEN * DMODEL;

  char* ws = (char*)d_ws;
  size_t off = 256;
  int* flag = (int*)ws;
  auto take = [&](size_t bytes) { char* p = ws + off; off += (bytes + 255) & ~255UL; return p; };
  const size_t XB = (size_t)BATCH * SLEN * DMODEL * 2;
  const size_t WB = (size_t)DMODEL * DMODEL * 2;
  unsigned short* Xq = (unsigned short*)take(XB);
  unsigned short* Xk = (unsigned short*)take(XB);
  unsigned short* Xv = (unsigned short*)take(XB);
  unsigned short* Wqb = (unsigned short*)take(WB);
  unsigned short* Wkb = (unsigned short*)take(WB);
  unsigned short* Wvb = (unsigned short*)take(WB);
  unsigned short* Wfcb = (unsigned short*)take(WB);
  unsigned short* Qh = (unsigned short*)take(XB);
  unsigned short* Kh = (unsigned short*)take(XB);
  unsigned short* Vh = (unsigned short*)take(XB);
  unsigned short* Vt = (unsigned short*)take(XB);
  unsigned short* ctx = (unsigned short*)take(XB);
  float* fc = (float*)take((size_t)BATCH * SLEN * DMODEL * 4);
  unsigned* mb = (unsigned*)take((size_t)BATCH * SLEN * 32 * 4);  // 1 MB bitmask

  detect_mask<<<1, 64, 0, stream>>>(mask, flag);
  mask_pack<<<BATCH * SLEN, 256, 0, stream>>>(mask, flag, mb);

  const int n8x = BATCH * SLEN * DMODEL / 8;
  const int n8w = DMODEL * DMODEL / 8;
  cvt_bf16_multi<<<dim3(n8x / 256, 3), 256, 0, stream>>>(inQ, inK, inV, nullptr,
                                                         Xq, Xk, Xv, nullptr, n8x);
  cvt_bf16_multi<<<dim3(n8w / 256, 4), 256, 0, stream>>>(WQ, WK, WV, WFC,
                                                         Wqb, Wkb, Wvb, Wfcb, n8w);

  dim3 gp(64, 8);
  gemm_nt<0><<<gp, 256, 0, stream>>>(Xq, Wqb, 1024, nullptr, Qh, 0.125f);
  gemm_nt<0><<<gp, 256, 0, stream>>>(Xk, Wkb, 1024, nullptr, Kh, 1.0f);
  gemm_nt<0><<<gp, 256, 0, stream>>>(Xv, Wvb, 1024, nullptr, Vh, 1.0f);

  transpose_v<<<dim3(16, 128), 256, 0, stream>>>(Vh, Vt);

  attn_scores<<<dim3(2, 128), 512, 0, stream>>>(Qh, Kh, mb, attn);

  pv_gemm<<<dim3(8, 128), 256, 0, stream>>>(attn, Vt, ctx);

  gemm_nt<1><<<gp, 256, 0, stream>>>(ctx, Wfcb, 1024, fc, nullptr, 1.0f);

  ln_kernel<<<BATCH * SLEN, 256, 0, stream>>>(fc, inQ, gamma, beta, out);
}

// Round 4
// 514.401 us; speedup vs baseline: 1.8138x; 1.0719x over previous
//
#include <hip/hip_runtime.h>

typedef __attribute__((ext_vector_type(8))) __bf16 bf16x8;
typedef __attribute__((ext_vector_type(4))) float f32x4;

#define SLEN 1024
#define DMODEL 1024
#define NHEADS 16
#define DKH 64
#define BATCH 8

__device__ __forceinline__ unsigned short f2bf(float f) {
  unsigned u = __builtin_bit_cast(unsigned, f);
  u += 0x7FFFu + ((u >> 16) & 1u);
  return (unsigned short)(u >> 16);
}

__device__ __forceinline__ void gload_lds16(const void* g, void* l) {
  __builtin_amdgcn_global_load_lds((const __attribute__((address_space(1))) unsigned int*)g,
                                   (__attribute__((address_space(3))) unsigned int*)l, 16, 0, 0);
}

// ---------------- mask dtype detection: flag=1 -> byte mask, 0 -> int32 mask
__global__ void detect_mask(const unsigned char* __restrict__ m, int* __restrict__ flag) {
  int t = threadIdx.x;
  unsigned any = 0;
  for (int j = t; j < 4096; j += 64) any |= m[j * 4 + 1];
  unsigned long long b = __ballot(any != 0);
  if (t == 0) *flag = (b != 0) ? 1 : 0;
}

// ---------------- bit-pack mask: one block per (b,q) row of 1024 -> 32 words
__global__ __launch_bounds__(256) void mask_pack(const unsigned char* __restrict__ m,
                                                 const int* __restrict__ flagp,
                                                 unsigned* __restrict__ mb) {
  long base = (long)blockIdx.x << 10;
  int tid = threadIdx.x;
  int flag = *flagp;
  unsigned nib;
  if (flag) {
    uchar4 v = ((const uchar4*)(m + base))[tid];
    nib = (v.x ? 1u : 0u) | (v.y ? 2u : 0u) | (v.z ? 4u : 0u) | (v.w ? 8u : 0u);
  } else {
    int4 v = ((const int4*)((const int*)m + base))[tid];
    nib = (v.x ? 1u : 0u) | (v.y ? 2u : 0u) | (v.z ? 4u : 0u) | (v.w ? 8u : 0u);
  }
  __shared__ unsigned char nibs[256];
  nibs[tid] = (unsigned char)nib;
  __syncthreads();
  if (tid < 32) {
    unsigned wv = 0;
#pragma unroll
    for (int i = 0; i < 8; i++) wv |= ((unsigned)nibs[tid * 8 + i]) << (i * 4);
    mb[((long)blockIdx.x << 5) + tid] = wv;
  }
}

// ---------------- fp32 -> bf16 bulk convert, up to 4 tensors via blockIdx.y
__global__ __launch_bounds__(256) void cvt_bf16_multi(
    const float* __restrict__ p0, const float* __restrict__ p1,
    const float* __restrict__ p2, const float* __restrict__ p3,
    unsigned short* __restrict__ o0, unsigned short* __restrict__ o1,
    unsigned short* __restrict__ o2, unsigned short* __restrict__ o3, int n8) {
  int which = blockIdx.y;
  const float* in = which == 0 ? p0 : which == 1 ? p1 : which == 2 ? p2 : p3;
  unsigned short* o = which == 0 ? o0 : which == 1 ? o1 : which == 2 ? o2 : o3;
  int i = blockIdx.x * 256 + threadIdx.x;
  if (i >= n8) return;
  const float4* p = (const float4*)in;
  float4 f0 = p[2 * i], f1 = p[2 * i + 1];
  union { unsigned short us[8]; uint4 v; } pk;
  pk.us[0] = f2bf(f0.x); pk.us[1] = f2bf(f0.y); pk.us[2] = f2bf(f0.z); pk.us[3] = f2bf(f0.w);
  pk.us[4] = f2bf(f1.x); pk.us[5] = f2bf(f1.y); pk.us[6] = f2bf(f1.z); pk.us[7] = f2bf(f1.w);
  ((uint4*)o)[i] = pk.v;
}

// ---------------- transpose V per (b,h): [1024][64] -> [64][1024]
__global__ __launch_bounds__(256) void transpose_v(const unsigned short* __restrict__ Vh,
                                                   unsigned short* __restrict__ Vt) {
  __shared__ unsigned short t[64][65];
  int s0 = blockIdx.x * 64;
  long zo = (long)blockIdx.y * (SLEN * DKH);
  int tid = threadIdx.x;
  for (int i = tid; i < 4096; i += 256) {
    int r = i >> 6, c = i & 63;
    t[r][c] = Vh[zo + (long)(s0 + r) * 64 + c];
  }
  __syncthreads();
  for (int i = tid; i < 4096; i += 256) {
    int d = i >> 6, sc = i & 63;
    Vt[zo + (long)d * SLEN + s0 + sc] = t[sc][d];
  }
}

// ---------------- merged QKV projection GEMM (z = 0/1/2 -> Q/K/V)
// A,B bf16 NT; out bf16 head layout [b][h][s][64]; Q pre-scaled 0.125
__global__ __launch_bounds__(256) void gemm_proj3(
    const unsigned short* __restrict__ A0, const unsigned short* __restrict__ A1,
    const unsigned short* __restrict__ A2, const unsigned short* __restrict__ B0,
    const unsigned short* __restrict__ B1, const unsigned short* __restrict__ B2,
    unsigned short* __restrict__ O0, unsigned short* __restrict__ O1,
    unsigned short* __restrict__ O2) {
  constexpr int BM = 128, BN = 128, BKE = 32;
  constexpr int WM = 64, WN = 64, FM = 4, FN = 4;
  const int z = blockIdx.z;
  const unsigned short* Ab = z == 0 ? A0 : z == 1 ? A1 : A2;
  const unsigned short* Bb = z == 0 ? B0 : z == 1 ? B1 : B2;
  unsigned short* obf = z == 0 ? O0 : z == 1 ? O1 : O2;
  const float scale = z == 0 ? 0.125f : 1.0f;

  const int m0 = blockIdx.x * BM;
  const int n0 = blockIdx.y * BN;
  const int tid = threadIdx.x;
  const int l = tid & 63;
  const int w = tid >> 6;
  const int wr = w >> 1, wc = w & 1;

  __shared__ __attribute__((aligned(16))) unsigned short As[BM * BKE];
  __shared__ __attribute__((aligned(16))) unsigned short Bs[BN * BKE];

  f32x4 acc[FM][FN];
#pragma unroll
  for (int i = 0; i < FM; i++)
#pragma unroll
    for (int j = 0; j < FN; j++)
      acc[i][j] = f32x4{0.f, 0.f, 0.f, 0.f};

  const int kread = (l >> 4) << 3;
  const int rl = l & 15;

  for (int k0 = 0; k0 < 1024; k0 += BKE) {
    __syncthreads();
#pragma unroll
    for (int i = 0; i < 2; i++) {
      int c = tid + i * 256;
      int row = c >> 2, kc = (c & 3) << 3;
      gload_lds16(Ab + (long)(m0 + row) * 1024 + (k0 + kc), &As[c * 8]);
    }
#pragma unroll
    for (int i = 0; i < 2; i++) {
      int c = tid + i * 256;
      int row = c >> 2, kc = (c & 3) << 3;
      gload_lds16(Bb + (long)(n0 + row) * 1024 + (k0 + kc), &Bs[c * 8]);
    }
    __syncthreads();

    bf16x8 af[FM], bfr[FN];
#pragma unroll
    for (int mi = 0; mi < FM; mi++)
      af[mi] = *(const bf16x8*)&As[(wr * WM + mi * 16 + rl) * BKE + kread];
#pragma unroll
    for (int ni = 0; ni < FN; ni++)
      bfr[ni] = *(const bf16x8*)&Bs[(wc * WN + ni * 16 + rl) * BKE + kread];
#pragma unroll
    for (int mi = 0; mi < FM; mi++)
#pragma unroll
      for (int ni = 0; ni < FN; ni++)
        acc[mi][ni] = __builtin_amdgcn_mfma_f32_16x16x32_bf16(af[mi], bfr[ni], acc[mi][ni], 0, 0, 0);
  }

  const int r0 = (l >> 4) << 2;
  const int cc = l & 15;
#pragma unroll
  for (int mi = 0; mi < FM; mi++) {
#pragma unroll
    for (int ni = 0; ni < FN; ni++) {
      f32x4 v = acc[mi][ni];
      int row = m0 + wr * WM + mi * 16 + r0;
      int col = n0 + wc * WN + ni * 16 + cc;
#pragma unroll
      for (int j = 0; j < 4; j++) {
        int rr = row + j;
        long idx = (((long)((rr >> 10) * 16 + (col >> 6)) * 1024 + (rr & 1023)) << 6) + (col & 63);
        obf[idx] = f2bf(v[j] * scale);
      }
    }
  }
}

// ---------------- FC GEMM: fp32 out row-major (A=ctx bf16, B=Wfc bf16)
__global__ __launch_bounds__(256) void gemm_fc(
    const unsigned short* __restrict__ Ab, const unsigned short* __restrict__ Bb,
    float* __restrict__ of32) {
  constexpr int BM = 128, BN = 128, BKE = 32;
  constexpr int WM = 64, WN = 64, FM = 4, FN = 4;
  const int m0 = blockIdx.x * BM;
  const int n0 = blockIdx.y * BN;
  const int tid = threadIdx.x;
  const int l = tid & 63;
  const int w = tid >> 6;
  const int wr = w >> 1, wc = w & 1;

  __shared__ __attribute__((aligned(16))) unsigned short As[BM * BKE];
  __shared__ __attribute__((aligned(16))) unsigned short Bs[BN * BKE];

  f32x4 acc[FM][FN];
#pragma unroll
  for (int i = 0; i < FM; i++)
#pragma unroll
    for (int j = 0; j < FN; j++)
      acc[i][j] = f32x4{0.f, 0.f, 0.f, 0.f};

  const int kread = (l >> 4) << 3;
  const int rl = l & 15;

  for (int k0 = 0; k0 < 1024; k0 += BKE) {
    __syncthreads();
#pragma unroll
    for (int i = 0; i < 2; i++) {
      int c = tid + i * 256;
      int row = c >> 2, kc = (c & 3) << 3;
      gload_lds16(Ab + (long)(m0 + row) * 1024 + (k0 + kc), &As[c * 8]);
    }
#pragma unroll
    for (int i = 0; i < 2; i++) {
      int c = tid + i * 256;
      int row = c >> 2, kc = (c & 3) << 3;
      gload_lds16(Bb + (long)(n0 + row) * 1024 + (k0 + kc), &Bs[c * 8]);
    }
    __syncthreads();

    bf16x8 af[FM], bfr[FN];
#pragma unroll
    for (int mi = 0; mi < FM; mi++)
      af[mi] = *(const bf16x8*)&As[(wr * WM + mi * 16 + rl) * BKE + kread];
#pragma unroll
    for (int ni = 0; ni < FN; ni++)
      bfr[ni] = *(const bf16x8*)&Bs[(wc * WN + ni * 16 + rl) * BKE + kread];
#pragma unroll
    for (int mi = 0; mi < FM; mi++)
#pragma unroll
      for (int ni = 0; ni < FN; ni++)
        acc[mi][ni] = __builtin_amdgcn_mfma_f32_16x16x32_bf16(af[mi], bfr[ni], acc[mi][ni], 0, 0, 0);
  }

  const int r0 = (l >> 4) << 2;
  const int cc = l & 15;
#pragma unroll
  for (int mi = 0; mi < FM; mi++) {
#pragma unroll
    for (int ni = 0; ni < FN; ni++) {
      f32x4 v = acc[mi][ni];
      int row = m0 + wr * WM + mi * 16 + r0;
      int col = n0 + wc * WN + ni * 16 + cc;
#pragma unroll
      for (int j = 0; j < 4; j++)
        of32[((long)(row + j) << 10) + col] = v[j];
    }
  }
}

// ---------------- fused scores+mask+softmax+attnwrite+PV, K/V L2-direct
// grid (8, 128): block = (b,h) x 128 q-rows; 256 thr (4 waves); 8 subtiles of 16
__global__ __launch_bounds__(256) void attn_fused2(
    const unsigned short* __restrict__ Qh, const unsigned short* __restrict__ Kh,
    const unsigned short* __restrict__ Vt, const unsigned* __restrict__ mb,
    float* __restrict__ attn, unsigned short* __restrict__ ctx) {
  const int z = blockIdx.y;
  const int b = z >> 4, h = z & 15;
  const int tid = threadIdx.x, l = tid & 63, w = tid >> 6;
  const int rl = l & 15, hi = l >> 4;

  __shared__ __attribute__((aligned(16))) unsigned short Pl[16 * 1024];  // 32 KB swz
  __shared__ __attribute__((aligned(16))) unsigned short Pc[16 * 64];    // 2 KB
  __shared__ float redm[4][16], reds[4][16];

  const long bh = (long)z * (SLEN * DKH);
  const unsigned short* Kb = Kh + bh;
  const unsigned short* Vb = Vt + bh;
  const long abase = (long)z << 20;

  for (int s = 0; s < 8; s++) {
    const int q0 = blockIdx.x * 128 + s * 16;
    const unsigned short* qp = Qh + bh + (long)(q0 + rl) * 64 + hi * 8;
    bf16x8 qf0 = *(const bf16x8*)qp;
    bf16x8 qf1 = *(const bf16x8*)(qp + 32);

    f32x4 acc[16];
#pragma unroll
    for (int t = 0; t < 16; t++) acc[t] = f32x4{0.f, 0.f, 0.f, 0.f};

    // scores: wave w owns cols [w*256, w*256+256)
#pragma unroll
    for (int t = 0; t < 16; t++) {
      int col = w * 256 + t * 16 + rl;
      const unsigned short* kp = Kb + (long)col * 64 + hi * 8;
      bf16x8 k0 = *(const bf16x8*)kp;
      bf16x8 k1 = *(const bf16x8*)(kp + 32);
      acc[t] = __builtin_amdgcn_mfma_f32_16x16x32_bf16(qf0, k0, acc[t], 0, 0, 0);
      acc[t] = __builtin_amdgcn_mfma_f32_16x16x32_bf16(qf1, k1, acc[t], 0, 0, 0);
    }

    // mask words
    unsigned mw[4][8];
#pragma unroll
    for (int j = 0; j < 4; j++) {
      int q = q0 + hi * 4 + j;
      const uint4* wp = (const uint4*)(mb + (((long)((b << 10) | q)) << 5) + w * 8);
      uint4 w0 = wp[0], w1 = wp[1];
      mw[j][0] = w0.x; mw[j][1] = w0.y; mw[j][2] = w0.z; mw[j][3] = w0.w;
      mw[j][4] = w1.x; mw[j][5] = w1.y; mw[j][6] = w1.z; mw[j][7] = w1.w;
    }

    float mx[4] = {-3.0e38f, -3.0e38f, -3.0e38f, -3.0e38f};
#pragma unroll
    for (int t = 0; t < 16; t++) {
#pragma unroll
      for (int j = 0; j < 4; j++) {
        float v = ((mw[j][t >> 1] >> (rl + ((t & 1) << 4))) & 1u) ? -1.0e9f : acc[t][j];
        acc[t][j] = v;
        mx[j] = fmaxf(mx[j], v);
      }
    }
#pragma unroll
    for (int j = 0; j < 4; j++) {
      mx[j] = fmaxf(mx[j], __shfl_xor(mx[j], 1));
      mx[j] = fmaxf(mx[j], __shfl_xor(mx[j], 2));
      mx[j] = fmaxf(mx[j], __shfl_xor(mx[j], 4));
      mx[j] = fmaxf(mx[j], __shfl_xor(mx[j], 8));
    }
    if (rl == 0) {
#pragma unroll
      for (int j = 0; j < 4; j++) redm[w][hi * 4 + j] = mx[j];
    }
    __syncthreads();
    float m4[4];
#pragma unroll
    for (int j = 0; j < 4; j++) {
      int r = hi * 4 + j;
      m4[j] = fmaxf(fmaxf(redm[0][r], redm[1][r]), fmaxf(redm[2][r], redm[3][r]));
    }

    float sum[4] = {0.f, 0.f, 0.f, 0.f};
#pragma unroll
    for (int t = 0; t < 16; t++)
#pragma unroll
      for (int j = 0; j < 4; j++) {
        float e = __expf(acc[t][j] - m4[j]);
        acc[t][j] = e;
        sum[j] += e;
      }
#pragma unroll
    for (int j = 0; j < 4; j++) {
      sum[j] += __shfl_xor(sum[j], 1);
      sum[j] += __shfl_xor(sum[j], 2);
      sum[j] += __shfl_xor(sum[j], 4);
      sum[j] += __shfl_xor(sum[j], 8);
    }
    if (rl == 0) {
#pragma unroll
      for (int j = 0; j < 4; j++) reds[w][hi * 4 + j] = sum[j];
    }
    __syncthreads();
    float inv[4];
#pragma unroll
    for (int j = 0; j < 4; j++) {
      int r = hi * 4 + j;
      inv[j] = 1.0f / (reds[0][r] + reds[1][r] + reds[2][r] + reds[3][r]);
    }

    // normalize: write attn (global) + P bf16 (LDS, XOR-swizzled)
#pragma unroll
    for (int t = 0; t < 16; t++) {
      int col = w * 256 + t * 16 + rl;
#pragma unroll
      for (int j = 0; j < 4; j++) {
        int r = hi * 4 + j;
        float p = acc[t][j] * inv[j];
        attn[abase + (((long)(q0 + r)) << 10) + col] = p;
        *(unsigned short*)((char*)Pl + r * 2048 + ((col * 2) ^ ((r & 7) << 4))) = f2bf(p);
      }
    }
    __syncthreads();

    // PV: wave w owns d-tile w (d = w*16 + rl); V from L2, P from LDS
    f32x4 c2 = f32x4{0.f, 0.f, 0.f, 0.f};
#pragma unroll
    for (int ks = 0; ks < 32; ks++) {
      bf16x8 af = *(const bf16x8*)((const char*)Pl + rl * 2048 + ((ks * 64 + hi * 16) ^ ((rl & 7) << 4)));
      bf16x8 vf = *(const bf16x8*)(Vb + (long)(w * 16 + rl) * 1024 + ks * 32 + hi * 8);
      c2 = __builtin_amdgcn_mfma_f32_16x16x32_bf16(af, vf, c2, 0, 0, 0);
    }
#pragma unroll
    for (int j = 0; j < 4; j++) Pc[(hi * 4 + j) * 64 + w * 16 + rl] = f2bf(c2[j]);
    __syncthreads();
    {
      int qr = tid >> 4, dg = (tid & 15) << 2;
      uint2 v = *(const uint2*)&Pc[qr * 64 + dg];
      *(uint2*)&ctx[((long)(b * 1024 + q0 + qr) << 10) + h * 64 + dg] = v;
    }
  }
}

// ---------------- residual + LayerNorm, one block per row
__global__ __launch_bounds__(256) void ln_kernel(const float* __restrict__ fc,
                                                 const float* __restrict__ inQ,
                                                 const float* __restrict__ gamma,
                                                 const float* __restrict__ beta,
                                                 float* __restrict__ out) {
  long base = (long)blockIdx.x << 10;
  int tid = threadIdx.x, l = tid & 63, w = tid >> 6;
  float4 a = ((const float4*)(fc + base))[tid];
  float4 b = ((const float4*)(inQ + base))[tid];
  float4 x; x.x = a.x + b.x; x.y = a.y + b.y; x.z = a.z + b.z; x.w = a.w + b.w;
  float s = x.x + x.y + x.z + x.w;
  float q = x.x * x.x + x.y * x.y + x.z * x.z + x.w * x.w;
  for (int o = 32; o; o >>= 1) { s += __shfl_xor(s, o); q += __shfl_xor(q, o); }
  __shared__ float rs[4], rq[4];
  if (l == 0) { rs[w] = s; rq[w] = q; }
  __syncthreads();
  s = rs[0] + rs[1] + rs[2] + rs[3];
  q = rq[0] + rq[1] + rq[2] + rq[3];
  float mu = s * (1.0f / 1024.0f);
  float var = q * (1.0f / 1024.0f) - mu * mu;
  float rstd = rsqrtf(var + 1e-5f);
  float4 g = ((const float4*)gamma)[tid];
  float4 be = ((const float4*)beta)[tid];
  float4 o4;
  o4.x = (x.x - mu) * rstd * g.x + be.x;
  o4.y = (x.y - mu) * rstd * g.y + be.y;
  o4.z = (x.z - mu) * rstd * g.z + be.z;
  o4.w = (x.w - mu) * rstd * g.w + be.w;
  ((float4*)(out + base))[tid] = o4;
}

extern "C" void kernel_launch(void* const* d_in, const int* in_sizes, int n_in,
                              void* d_out, int out_size, void* d_ws, size_t ws_size,
                              hipStream_t stream) {
  const float* inQ = (const float*)d_in[0];
  const float* inK = (const float*)d_in[1];
  const float* inV = (const float*)d_in[2];
  const unsigned char* mask = (const unsigned char*)d_in[3];
  const float* WQ = (const float*)d_in[4];
  const float* WK = (const float*)d_in[5];
  const float* WV = (const float*)d_in[6];
  const float* WFC = (const float*)d_in[7];
  const float* gamma = (const float*)d_in[8];
  const float* beta = (const float*)d_in[9];

  float* out = (float*)d_out;
  float* attn = out + (size_t)BATCH * SLEN * DMODEL;

  char* ws = (char*)d_ws;
  size_t off = 256;
  int* flag = (int*)ws;
  auto take = [&](size_t bytes) { char* p = ws + off; off += (bytes + 255) & ~255UL; return p; };
  const size_t XB = (size_t)BATCH * SLEN * DMODEL * 2;
  const size_t WB = (size_t)DMODEL * DMODEL * 2;
  unsigned short* Xq = (unsigned short*)take(XB);
  unsigned short* Xk = (unsigned short*)take(XB);
  unsigned short* Xv = (unsigned short*)take(XB);
  unsigned short* Wqb = (unsigned short*)take(WB);
  unsigned short* Wkb = (unsigned short*)take(WB);
  unsigned short* Wvb = (unsigned short*)take(WB);
  unsigned short* Wfcb = (unsigned short*)take(WB);
  unsigned short* Qh = (unsigned short*)take(XB);
  unsigned short* Kh = (unsigned short*)take(XB);
  unsigned short* Vh = (unsigned short*)take(XB);
  unsigned short* Vt = (unsigned short*)take(XB);
  unsigned short* ctx = (unsigned short*)take(XB);
  float* fc = (float*)take((size_t)BATCH * SLEN * DMODEL * 4);
  unsigned* mb = (unsigned*)take((size_t)BATCH * SLEN * 32 * 4);  // 1 MB bitmask

  detect_mask<<<1, 64, 0, stream>>>(mask, flag);
  mask_pack<<<BATCH * SLEN, 256, 0, stream>>>(mask, flag, mb);

  const int n8x = BATCH * SLEN * DMODEL / 8;
  const int n8w = DMODEL * DMODEL / 8;
  cvt_bf16_multi<<<dim3(n8x / 256, 3), 256, 0, stream>>>(inQ, inK, inV, nullptr,
                                                         Xq, Xk, Xv, nullptr, n8x);
  cvt_bf16_multi<<<dim3(n8w / 256, 4), 256, 0, stream>>>(WQ, WK, WV, WFC,
                                                         Wqb, Wkb, Wvb, Wfcb, n8w);

  gemm_proj3<<<dim3(64, 8, 3), 256, 0, stream>>>(Xq, Xk, Xv, Wqb, Wkb, Wvb, Qh, Kh, Vh);

  transpose_v<<<dim3(16, 128), 256, 0, stream>>>(Vh, Vt);

  attn_fused2<<<dim3(8, 128), 256, 0, stream>>>(Qh, Kh, Vt, mb, attn, ctx);

  gemm_fc<<<dim3(64, 8), 256, 0, stream>>>(ctx, Wfcb, fc);

  ln_kernel<<<BATCH * SLEN, 256, 0, stream>>>(fc, inQ, gamma, beta, out);
}

// Round 6
// 449.340 us; speedup vs baseline: 2.0764x; 1.1448x over previous
//
#include <hip/hip_runtime.h>

typedef __attribute__((ext_vector_type(8))) __bf16 bf16x8;
typedef __attribute__((ext_vector_type(4))) float f32x4;

#define SLEN 1024
#define DMODEL 1024
#define NHEADS 16
#define DKH 64
#define BATCH 8

__device__ __forceinline__ unsigned short f2bf(float f) {
  unsigned u = __builtin_bit_cast(unsigned, f);
  u += 0x7FFFu + ((u >> 16) & 1u);
  return (unsigned short)(u >> 16);
}

__device__ __forceinline__ void gload_lds16(const void* g, void* l) {
  __builtin_amdgcn_global_load_lds((const __attribute__((address_space(1))) unsigned int*)g,
                                   (__attribute__((address_space(3))) unsigned int*)l, 16, 0, 0);
}

// ---------------- mask dtype detection: flag=1 -> byte mask, 0 -> int32 mask
__global__ void detect_mask(const unsigned char* __restrict__ m, int* __restrict__ flag) {
  int t = threadIdx.x;
  unsigned any = 0;
  for (int j = t; j < 4096; j += 64) any |= m[j * 4 + 1];
  unsigned long long b = __ballot(any != 0);
  if (t == 0) *flag = (b != 0) ? 1 : 0;
}

// ---------------- bit-pack mask: one block per (b,q) row of 1024 -> 32 words
__global__ __launch_bounds__(256) void mask_pack(const unsigned char* __restrict__ m,
                                                 const int* __restrict__ flagp,
                                                 unsigned* __restrict__ mb) {
  long base = (long)blockIdx.x << 10;
  int tid = threadIdx.x;
  int flag = *flagp;
  unsigned nib;
  if (flag) {
    uchar4 v = ((const uchar4*)(m + base))[tid];
    nib = (v.x ? 1u : 0u) | (v.y ? 2u : 0u) | (v.z ? 4u : 0u) | (v.w ? 8u : 0u);
  } else {
    int4 v = ((const int4*)((const int*)m + base))[tid];
    nib = (v.x ? 1u : 0u) | (v.y ? 2u : 0u) | (v.z ? 4u : 0u) | (v.w ? 8u : 0u);
  }
  __shared__ unsigned char nibs[256];
  nibs[tid] = (unsigned char)nib;
  __syncthreads();
  if (tid < 32) {
    unsigned wv = 0;
#pragma unroll
    for (int i = 0; i < 8; i++) wv |= ((unsigned)nibs[tid * 8 + i]) << (i * 4);
    mb[((long)blockIdx.x << 5) + tid] = wv;
  }
}

// ---------------- fp32 -> bf16 bulk convert, up to 4 tensors via blockIdx.y
__global__ __launch_bounds__(256) void cvt_bf16_multi(
    const float* __restrict__ p0, const float* __restrict__ p1,
    const float* __restrict__ p2, const float* __restrict__ p3,
    unsigned short* __restrict__ o0, unsigned short* __restrict__ o1,
    unsigned short* __restrict__ o2, unsigned short* __restrict__ o3, int n8) {
  int which = blockIdx.y;
  const float* in = which == 0 ? p0 : which == 1 ? p1 : which == 2 ? p2 : p3;
  unsigned short* o = which == 0 ? o0 : which == 1 ? o1 : which == 2 ? o2 : o3;
  int i = blockIdx.x * 256 + threadIdx.x;
  if (i >= n8) return;
  const float4* p = (const float4*)in;
  float4 f0 = p[2 * i], f1 = p[2 * i + 1];
  union { unsigned short us[8]; uint4 v; } pk;
  pk.us[0] = f2bf(f0.x); pk.us[1] = f2bf(f0.y); pk.us[2] = f2bf(f0.z); pk.us[3] = f2bf(f0.w);
  pk.us[4] = f2bf(f1.x); pk.us[5] = f2bf(f1.y); pk.us[6] = f2bf(f1.z); pk.us[7] = f2bf(f1.w);
  ((uint4*)o)[i] = pk.v;
}

// ---------------- transpose V per (b,h): [1024][64] -> [64][1024]
__global__ __launch_bounds__(256) void transpose_v(const unsigned short* __restrict__ Vh,
                                                   unsigned short* __restrict__ Vt) {
  __shared__ unsigned short t[64][65];
  int s0 = blockIdx.x * 64;
  long zo = (long)blockIdx.y * (SLEN * DKH);
  int tid = threadIdx.x;
  for (int i = tid; i < 4096; i += 256) {
    int r = i >> 6, c = i & 63;
    t[r][c] = Vh[zo + (long)(s0 + r) * 64 + c];
  }
  __syncthreads();
  for (int i = tid; i < 4096; i += 256) {
    int d = i >> 6, sc = i & 63;
    Vt[zo + (long)d * SLEN + s0 + sc] = t[sc][d];
  }
}

// ---------------- merged QKV projection GEMM (z = 0/1/2 -> Q/K/V)
__global__ __launch_bounds__(256) void gemm_proj3(
    const unsigned short* __restrict__ A0, const unsigned short* __restrict__ A1,
    const unsigned short* __restrict__ A2, const unsigned short* __restrict__ B0,
    const unsigned short* __restrict__ B1, const unsigned short* __restrict__ B2,
    unsigned short* __restrict__ O0, unsigned short* __restrict__ O1,
    unsigned short* __restrict__ O2) {
  constexpr int BM = 128, BN = 128, BKE = 32;
  constexpr int WM = 64, WN = 64, FM = 4, FN = 4;
  const int z = blockIdx.z;
  const unsigned short* Ab = z == 0 ? A0 : z == 1 ? A1 : A2;
  const unsigned short* Bb = z == 0 ? B0 : z == 1 ? B1 : B2;
  unsigned short* obf = z == 0 ? O0 : z == 1 ? O1 : O2;
  const float scale = z == 0 ? 0.125f : 1.0f;

  const int m0 = blockIdx.x * BM;
  const int n0 = blockIdx.y * BN;
  const int tid = threadIdx.x;
  const int l = tid & 63;
  const int w = tid >> 6;
  const int wr = w >> 1, wc = w & 1;

  __shared__ __attribute__((aligned(16))) unsigned short As[BM * BKE];
  __shared__ __attribute__((aligned(16))) unsigned short Bs[BN * BKE];

  f32x4 acc[FM][FN];
#pragma unroll
  for (int i = 0; i < FM; i++)
#pragma unroll
    for (int j = 0; j < FN; j++)
      acc[i][j] = f32x4{0.f, 0.f, 0.f, 0.f};

  const int kread = (l >> 4) << 3;
  const int rl = l & 15;

  for (int k0 = 0; k0 < 1024; k0 += BKE) {
    __syncthreads();
#pragma unroll
    for (int i = 0; i < 2; i++) {
      int c = tid + i * 256;
      int row = c >> 2, kc = (c & 3) << 3;
      gload_lds16(Ab + (long)(m0 + row) * 1024 + (k0 + kc), &As[c * 8]);
    }
#pragma unroll
    for (int i = 0; i < 2; i++) {
      int c = tid + i * 256;
      int row = c >> 2, kc = (c & 3) << 3;
      gload_lds16(Bb + (long)(n0 + row) * 1024 + (k0 + kc), &Bs[c * 8]);
    }
    __syncthreads();

    bf16x8 af[FM], bfr[FN];
#pragma unroll
    for (int mi = 0; mi < FM; mi++)
      af[mi] = *(const bf16x8*)&As[(wr * WM + mi * 16 + rl) * BKE + kread];
#pragma unroll
    for (int ni = 0; ni < FN; ni++)
      bfr[ni] = *(const bf16x8*)&Bs[(wc * WN + ni * 16 + rl) * BKE + kread];
#pragma unroll
    for (int mi = 0; mi < FM; mi++)
#pragma unroll
      for (int ni = 0; ni < FN; ni++)
        acc[mi][ni] = __builtin_amdgcn_mfma_f32_16x16x32_bf16(af[mi], bfr[ni], acc[mi][ni], 0, 0, 0);
  }

  const int r0 = (l >> 4) << 2;
  const int cc = l & 15;
#pragma unroll
  for (int mi = 0; mi < FM; mi++) {
#pragma unroll
    for (int ni = 0; ni < FN; ni++) {
      f32x4 v = acc[mi][ni];
      int row = m0 + wr * WM + mi * 16 + r0;
      int col = n0 + wc * WN + ni * 16 + cc;
#pragma unroll
      for (int j = 0; j < 4; j++) {
        int rr = row + j;
        long idx = (((long)((rr >> 10) * 16 + (col >> 6)) * 1024 + (rr & 1023)) << 6) + (col & 63);
        obf[idx] = f2bf(v[j] * scale);
      }
    }
  }
}

// ---------------- FC GEMM: fp32 out row-major (A=ctx bf16, B=Wfc bf16)
__global__ __launch_bounds__(256) void gemm_fc(
    const unsigned short* __restrict__ Ab, const unsigned short* __restrict__ Bb,
    float* __restrict__ of32) {
  constexpr int BM = 128, BN = 128, BKE = 32;
  constexpr int WM = 64, WN = 64, FM = 4, FN = 4;
  const int m0 = blockIdx.x * BM;
  const int n0 = blockIdx.y * BN;
  const int tid = threadIdx.x;
  const int l = tid & 63;
  const int w = tid >> 6;
  const int wr = w >> 1, wc = w & 1;

  __shared__ __attribute__((aligned(16))) unsigned short As[BM * BKE];
  __shared__ __attribute__((aligned(16))) unsigned short Bs[BN * BKE];

  f32x4 acc[FM][FN];
#pragma unroll
  for (int i = 0; i < FM; i++)
#pragma unroll
    for (int j = 0; j < FN; j++)
      acc[i][j] = f32x4{0.f, 0.f, 0.f, 0.f};

  const int kread = (l >> 4) << 3;
  const int rl = l & 15;

  for (int k0 = 0; k0 < 1024; k0 += BKE) {
    __syncthreads();
#pragma unroll
    for (int i = 0; i < 2; i++) {
      int c = tid + i * 256;
      int row = c >> 2, kc = (c & 3) << 3;
      gload_lds16(Ab + (long)(m0 + row) * 1024 + (k0 + kc), &As[c * 8]);
    }
#pragma unroll
    for (int i = 0; i < 2; i++) {
      int c = tid + i * 256;
      int row = c >> 2, kc = (c & 3) << 3;
      gload_lds16(Bb + (long)(n0 + row) * 1024 + (k0 + kc), &Bs[c * 8]);
    }
    __syncthreads();

    bf16x8 af[FM], bfr[FN];
#pragma unroll
    for (int mi = 0; mi < FM; mi++)
      af[mi] = *(const bf16x8*)&As[(wr * WM + mi * 16 + rl) * BKE + kread];
#pragma unroll
    for (int ni = 0; ni < FN; ni++)
      bfr[ni] = *(const bf16x8*)&Bs[(wc * WN + ni * 16 + rl) * BKE + kread];
#pragma unroll
    for (int mi = 0; mi < FM; mi++)
#pragma unroll
      for (int ni = 0; ni < FN; ni++)
        acc[mi][ni] = __builtin_amdgcn_mfma_f32_16x16x32_bf16(af[mi], bfr[ni], acc[mi][ni], 0, 0, 0);
  }

  const int r0 = (l >> 4) << 2;
  const int cc = l & 15;
#pragma unroll
  for (int mi = 0; mi < FM; mi++) {
#pragma unroll
    for (int ni = 0; ni < FN; ni++) {
      f32x4 v = acc[mi][ni];
      int row = m0 + wr * WM + mi * 16 + r0;
      int col = n0 + wc * WN + ni * 16 + cc;
#pragma unroll
      for (int j = 0; j < 4; j++)
        of32[((long)(row + j) << 10) + col] = v[j];
    }
  }
}

// ---------------- fused scores+mask+softmax+attnwrite+PV, K/V L2-direct
// 1-D grid 1024; XCD-locality decode: each XCD owns 16 z's (K+V = 4 MB = its L2)
__global__ __launch_bounds__(256) void attn_fused2(
    const unsigned short* __restrict__ Qh, const unsigned short* __restrict__ Kh,
    const unsigned short* __restrict__ Vt, const unsigned* __restrict__ mb,
    float* __restrict__ attn, unsigned short* __restrict__ ctx) {
  const int lin = blockIdx.x;
  const int xcd = lin & 7;
  const int k_ = lin >> 3;
  const int z = xcd + ((k_ >> 3) << 3);  // z % 8 == xcd
  const int qt = k_ & 7;
  const int b = z >> 4, h = z & 15;
  const int tid = threadIdx.x, l = tid & 63, w = tid >> 6;
  const int rl = l & 15, hi = l >> 4;

  __shared__ __attribute__((aligned(16))) unsigned short Pl[16 * 1024];  // 32 KB swz
  __shared__ __attribute__((aligned(16))) unsigned short Pc[16 * 64];    // 2 KB
  __shared__ float redm[4][16], reds[4][16];

  const long bh = (long)z * (SLEN * DKH);
  const unsigned short* Kb = Kh + bh;
  const unsigned short* Vb = Vt + bh;
  const long abase = (long)z << 20;

  for (int s = 0; s < 8; s++) {
    const int q0 = qt * 128 + s * 16;
    const unsigned short* qp = Qh + bh + (long)(q0 + rl) * 64 + hi * 8;
    bf16x8 qf0 = *(const bf16x8*)qp;
    bf16x8 qf1 = *(const bf16x8*)(qp + 32);

    f32x4 acc[16];
#pragma unroll
    for (int t = 0; t < 16; t++) acc[t] = f32x4{0.f, 0.f, 0.f, 0.f};

    // scores: wave w owns cols [w*256, w*256+256)
    __builtin_amdgcn_s_setprio(1);
#pragma unroll
    for (int t = 0; t < 16; t++) {
      int col = w * 256 + t * 16 + rl;
      const unsigned short* kp = Kb + (long)col * 64 + hi * 8;
      bf16x8 k0 = *(const bf16x8*)kp;
      bf16x8 k1 = *(const bf16x8*)(kp + 32);
      acc[t] = __builtin_amdgcn_mfma_f32_16x16x32_bf16(qf0, k0, acc[t], 0, 0, 0);
      acc[t] = __builtin_amdgcn_mfma_f32_16x16x32_bf16(qf1, k1, acc[t], 0, 0, 0);
    }
    __builtin_amdgcn_s_setprio(0);

    // mask words
    unsigned mw[4][8];
#pragma unroll
    for (int j = 0; j < 4; j++) {
      int q = q0 + hi * 4 + j;
      const uint4* wp = (const uint4*)(mb + (((long)((b << 10) | q)) << 5) + w * 8);
      uint4 w0 = wp[0], w1 = wp[1];
      mw[j][0] = w0.x; mw[j][1] = w0.y; mw[j][2] = w0.z; mw[j][3] = w0.w;
      mw[j][4] = w1.x; mw[j][5] = w1.y; mw[j][6] = w1.z; mw[j][7] = w1.w;
    }

    float mx[4] = {-3.0e38f, -3.0e38f, -3.0e38f, -3.0e38f};
#pragma unroll
    for (int t = 0; t < 16; t++) {
#pragma unroll
      for (int j = 0; j < 4; j++) {
        float v = ((mw[j][t >> 1] >> (rl + ((t & 1) << 4))) & 1u) ? -1.0e9f : acc[t][j];
        acc[t][j] = v;
        mx[j] = fmaxf(mx[j], v);
      }
    }
#pragma unroll
    for (int j = 0; j < 4; j++) {
      mx[j] = fmaxf(mx[j], __shfl_xor(mx[j], 1));
      mx[j] = fmaxf(mx[j], __shfl_xor(mx[j], 2));
      mx[j] = fmaxf(mx[j], __shfl_xor(mx[j], 4));
      mx[j] = fmaxf(mx[j], __shfl_xor(mx[j], 8));
    }
    if (rl == 0) {
#pragma unroll
      for (int j = 0; j < 4; j++) redm[w][hi * 4 + j] = mx[j];
    }
    __syncthreads();
    float m4[4];
#pragma unroll
    for (int j = 0; j < 4; j++) {
      int r = hi * 4 + j;
      m4[j] = fmaxf(fmaxf(redm[0][r], redm[1][r]), fmaxf(redm[2][r], redm[3][r]));
    }

    float sum[4] = {0.f, 0.f, 0.f, 0.f};
#pragma unroll
    for (int t = 0; t < 16; t++)
#pragma unroll
      for (int j = 0; j < 4; j++) {
        float e = __expf(acc[t][j] - m4[j]);
        acc[t][j] = e;
        sum[j] += e;
      }
#pragma unroll
    for (int j = 0; j < 4; j++) {
      sum[j] += __shfl_xor(sum[j], 1);
      sum[j] += __shfl_xor(sum[j], 2);
      sum[j] += __shfl_xor(sum[j], 4);
      sum[j] += __shfl_xor(sum[j], 8);
    }
    if (rl == 0) {
#pragma unroll
      for (int j = 0; j < 4; j++) reds[w][hi * 4 + j] = sum[j];
    }
    __syncthreads();
    float inv[4];
#pragma unroll
    for (int j = 0; j < 4; j++) {
      int r = hi * 4 + j;
      inv[j] = 1.0f / (reds[0][r] + reds[1][r] + reds[2][r] + reds[3][r]);
    }

    // normalize: nontemporal attn write (keep L2 for K/V) + P bf16 (LDS, swz)
#pragma unroll
    for (int t = 0; t < 16; t++) {
      int col = w * 256 + t * 16 + rl;
#pragma unroll
      for (int j = 0; j < 4; j++) {
        int r = hi * 4 + j;
        float p = acc[t][j] * inv[j];
        __builtin_nontemporal_store(p, &attn[abase + (((long)(q0 + r)) << 10) + col]);
        *(unsigned short*)((char*)Pl + r * 2048 + ((col * 2) ^ ((r & 7) << 4))) = f2bf(p);
      }
    }
    __syncthreads();

    // PV: wave w owns d-tile w (d = w*16 + rl); V from L2, P from LDS
    f32x4 c2 = f32x4{0.f, 0.f, 0.f, 0.f};
    __builtin_amdgcn_s_setprio(1);
#pragma unroll
    for (int ks = 0; ks < 32; ks++) {
      bf16x8 af = *(const bf16x8*)((const char*)Pl + rl * 2048 + ((ks * 64 + hi * 16) ^ ((rl & 7) << 4)));
      bf16x8 vf = *(const bf16x8*)(Vb + (long)(w * 16 + rl) * 1024 + ks * 32 + hi * 8);
      c2 = __builtin_amdgcn_mfma_f32_16x16x32_bf16(af, vf, c2, 0, 0, 0);
    }
    __builtin_amdgcn_s_setprio(0);
#pragma unroll
    for (int j = 0; j < 4; j++) Pc[(hi * 4 + j) * 64 + w * 16 + rl] = f2bf(c2[j]);
    __syncthreads();
    {
      int qr = tid >> 4, dg = (tid & 15) << 2;
      unsigned long long v = *(const unsigned long long*)&Pc[qr * 64 + dg];
      __builtin_nontemporal_store(
          v, (unsigned long long*)&ctx[((long)(b * 1024 + q0 + qr) << 10) + h * 64 + dg]);
    }
  }
}

// ---------------- residual + LayerNorm, one block per row
__global__ __launch_bounds__(256) void ln_kernel(const float* __restrict__ fc,
                                                 const float* __restrict__ inQ,
                                                 const float* __restrict__ gamma,
                                                 const float* __restrict__ beta,
                                                 float* __restrict__ out) {
  long base = (long)blockIdx.x << 10;
  int tid = threadIdx.x, l = tid & 63, w = tid >> 6;
  float4 a = ((const float4*)(fc + base))[tid];
  float4 b = ((const float4*)(inQ + base))[tid];
  float4 x; x.x = a.x + b.x; x.y = a.y + b.y; x.z = a.z + b.z; x.w = a.w + b.w;
  float s = x.x + x.y + x.z + x.w;
  float q = x.x * x.x + x.y * x.y + x.z * x.z + x.w * x.w;
  for (int o = 32; o; o >>= 1) { s += __shfl_xor(s, o); q += __shfl_xor(q, o); }
  __shared__ float rs[4], rq[4];
  if (l == 0) { rs[w] = s; rq[w] = q; }
  __syncthreads();
  s = rs[0] + rs[1] + rs[2] + rs[3];
  q = rq[0] + rq[1] + rq[2] + rq[3];
  float mu = s * (1.0f / 1024.0f);
  float var = q * (1.0f / 1024.0f) - mu * mu;
  float rstd = rsqrtf(var + 1e-5f);
  float4 g = ((const float4*)gamma)[tid];
  float4 be = ((const float4*)beta)[tid];
  float4 o4;
  o4.x = (x.x - mu) * rstd * g.x + be.x;
  o4.y = (x.y - mu) * rstd * g.y + be.y;
  o4.z = (x.z - mu) * rstd * g.z + be.z;
  o4.w = (x.w - mu) * rstd * g.w + be.w;
  ((float4*)(out + base))[tid] = o4;
}

extern "C" void kernel_launch(void* const* d_in, const int* in_sizes, int n_in,
                              void* d_out, int out_size, void* d_ws, size_t ws_size,
                              hipStream_t stream) {
  const float* inQ = (const float*)d_in[0];
  const float* inK = (const float*)d_in[1];
  const float* inV = (const float*)d_in[2];
  const unsigned char* mask = (const unsigned char*)d_in[3];
  const float* WQ = (const float*)d_in[4];
  const float* WK = (const float*)d_in[5];
  const float* WV = (const float*)d_in[6];
  const float* WFC = (const float*)d_in[7];
  const float* gamma = (const float*)d_in[8];
  const float* beta = (const float*)d_in[9];

  float* out = (float*)d_out;
  float* attn = out + (size_t)BATCH * SLEN * DMODEL;

  char* ws = (char*)d_ws;
  size_t off = 256;
  int* flag = (int*)ws;
  auto take = [&](size_t bytes) { char* p = ws + off; off += (bytes + 255) & ~255UL; return p; };
  const size_t XB = (size_t)BATCH * SLEN * DMODEL * 2;
  const size_t WB = (size_t)DMODEL * DMODEL * 2;
  unsigned short* Xq = (unsigned short*)take(XB);
  unsigned short* Xk = (unsigned short*)take(XB);
  unsigned short* Xv = (unsigned short*)take(XB);
  unsigned short* Wqb = (unsigned short*)take(WB);
  unsigned short* Wkb = (unsigned short*)take(WB);
  unsigned short* Wvb = (unsigned short*)take(WB);
  unsigned short* Wfcb = (unsigned short*)take(WB);
  unsigned short* Qh = (unsigned short*)take(XB);
  unsigned short* Kh = (unsigned short*)take(XB);
  unsigned short* Vh = (unsigned short*)take(XB);
  unsigned short* Vt = (unsigned short*)take(XB);
  unsigned short* ctx = (unsigned short*)take(XB);
  float* fc = (float*)take((size_t)BATCH * SLEN * DMODEL * 4);
  unsigned* mb = (unsigned*)take((size_t)BATCH * SLEN * 32 * 4);  // 1 MB bitmask

  detect_mask<<<1, 64, 0, stream>>>(mask, flag);
  mask_pack<<<BATCH * SLEN, 256, 0, stream>>>(mask, flag, mb);

  const int n8x = BATCH * SLEN * DMODEL / 8;
  const int n8w = DMODEL * DMODEL / 8;
  cvt_bf16_multi<<<dim3(n8x / 256, 3), 256, 0, stream>>>(inQ, inK, inV, nullptr,
                                                         Xq, Xk, Xv, nullptr, n8x);
  cvt_bf16_multi<<<dim3(n8w / 256, 4), 256, 0, stream>>>(WQ, WK, WV, WFC,
                                                         Wqb, Wkb, Wvb, Wfcb, n8w);

  gemm_proj3<<<dim3(64, 8, 3), 256, 0, stream>>>(Xq, Xk, Xv, Wqb, Wkb, Wvb, Qh, Kh, Vh);

  transpose_v<<<dim3(16, 128), 256, 0, stream>>>(Vh, Vt);

  attn_fused2<<<dim3(1024), 256, 0, stream>>>(Qh, Kh, Vt, mb, attn, ctx);

  gemm_fc<<<dim3(64, 8), 256, 0, stream>>>(ctx, Wfcb, fc);

  ln_kernel<<<BATCH * SLEN, 256, 0, stream>>>(fc, inQ, gamma, beta, out);
}